// Round 1
// baseline (135.278 us; speedup 1.0000x reference)
//
#include <hip/hip_runtime.h>

#define B 4096
#define S 200
#define EMB_DIM 128
#define HIDDEN 256
#define NUM_CLASSES 20
#define VOCAB 100000
#define RB 2               // batch rows per gather block
#define MR 8               // batch rows per MLP block

typedef __attribute__((ext_vector_type(8))) unsigned short ushort8;

// RNE float -> bf16 (inputs are finite, no NaN handling needed)
__device__ __forceinline__ unsigned short f2bf(float f) {
    unsigned u = __float_as_uint(f);
    unsigned r = u + 0x7fffu + ((u >> 16) & 1u);
    return (unsigned short)(r >> 16);
}

// ---------------------------------------------------------------------------
// Pass 1: stream-convert the fp32 table (51.2 MB, cold in HBM because the
// harness's 256 MiB ws re-poison flushes L3 every iteration) into a 25.6 MB
// bf16 table in d_ws. Sequential HBM reads at ~6 TB/s; the bf16 table it
// leaves behind is L3-resident for the gather and halves the gathered bytes.
// ---------------------------------------------------------------------------
__global__ __launch_bounds__(256) void convert_kernel(
    const float* __restrict__ emb,          // [VOCAB*EMB_DIM]
    unsigned short* __restrict__ embh)      // [VOCAB*EMB_DIM] bf16 bits
{
    const long i = ((long)blockIdx.x * 256 + threadIdx.x) * 8;
    const float4 a = *(const float4*)(emb + i);
    const float4 b = *(const float4*)(emb + i + 4);
    ushort8 o;
    o[0] = f2bf(a.x); o[1] = f2bf(a.y); o[2] = f2bf(a.z); o[3] = f2bf(a.w);
    o[4] = f2bf(b.x); o[5] = f2bf(b.y); o[6] = f2bf(b.z); o[7] = f2bf(b.w);
    *(ushort8*)(embh + i) = o;
}

// ---------------------------------------------------------------------------
// Pass 2: gather + mean-pool ONLY (MLP split out so W1 traffic no longer
// scales with this kernel's 2048-block grid). RB=2 rows/block, 256 threads.
// g = t>>4 (16 position groups), d = t&15 (16B slot of the 256B bf16 row).
// Full rounds cover 64 positions (4-deep ILP); a single tail round covers the
// remaining ceil(rem/16) 16-position steps via block-uniform scalar branches
// -> E[positions] drops from 132.5 to 108 (-18.5% gather loads + VALU).
// Positions >= L read row 0 (all zeros, padding_idx=0). fp32 accumulation.
// ---------------------------------------------------------------------------
__global__ __launch_bounds__(256) void gather_kernel(
    const int* __restrict__ x,              // [B, S]
    const int* __restrict__ lens,           // [B]
    const unsigned short* __restrict__ embh,// [VOCAB, EMB_DIM] bf16
    float* __restrict__ Pg)                 // [B, EMB_DIM] pooled output
{
    __shared__ int   sidx[RB][256];              // 2 KB
    __shared__ float tmp[16][16][8];             // 8 KB (group, slot, dim-in-slot)

    const int t  = threadIdx.x;
    const int b0 = blockIdx.x * RB;

    int Ls[RB];
    #pragma unroll
    for (int r = 0; r < RB; ++r) {
        Ls[r] = lens[b0 + r];
        int v = 0;
        if (t < Ls[r]) v = x[(long)(b0 + r) * S + t];   // L <= S = 200 < 256
        sidx[r][t] = v;
    }
    __syncthreads();

    const int g = t >> 4;   // position group 0..15
    const int d = t & 15;   // 16B slot within the 256B bf16 row

    for (int r = 0; r < RB; ++r) {
        const int L     = Ls[r];
        const int nJ    = (L + 15) >> 4;   // 1..13 16-position steps
        const int nFull = nJ >> 2;         // full 64-position rounds, 0..3
        const int tailJ = nJ & 3;          // leftover 16-position steps, 0..3

        float acc[4][8];
        #pragma unroll
        for (int j = 0; j < 4; ++j)
            #pragma unroll
            for (int f = 0; f < 8; ++f) acc[j][f] = 0.f;

        int cur[4], nxt[4];
        #pragma unroll
        for (int j = 0; j < 4; ++j) cur[j] = sidx[r][g + 16 * j];

        for (int it = 0; it < nFull; ++it) {
            uint4 v[4];
            #pragma unroll
            for (int j = 0; j < 4; ++j)
                v[j] = *(const uint4*)(embh + (long)cur[j] * EMB_DIM + d * 8);

            // prefetch next round's indices before the vmcnt wait
            // (always safe: max index = nFull*64 + 15 + 48 <= 255)
            const int nb = (it + 1) << 6;
            #pragma unroll
            for (int j = 0; j < 4; ++j) nxt[j] = sidx[r][nb + g + 16 * j];

            #pragma unroll
            for (int j = 0; j < 4; ++j) {
                const unsigned c0 = v[j].x, c1 = v[j].y, c2 = v[j].z, c3 = v[j].w;
                acc[j][0] += __uint_as_float(c0 << 16);
                acc[j][1] += __uint_as_float(c0 & 0xffff0000u);
                acc[j][2] += __uint_as_float(c1 << 16);
                acc[j][3] += __uint_as_float(c1 & 0xffff0000u);
                acc[j][4] += __uint_as_float(c2 << 16);
                acc[j][5] += __uint_as_float(c2 & 0xffff0000u);
                acc[j][6] += __uint_as_float(c3 << 16);
                acc[j][7] += __uint_as_float(c3 & 0xffff0000u);
            }
            #pragma unroll
            for (int j = 0; j < 4; ++j) cur[j] = nxt[j];
        }

        if (tailJ) {
            // j < tailJ is block-uniform -> scalar branches, no divergence.
            uint4 v[4];
            #pragma unroll
            for (int j = 0; j < 4; ++j)
                if (j < tailJ)
                    v[j] = *(const uint4*)(embh + (long)cur[j] * EMB_DIM + d * 8);
            #pragma unroll
            for (int j = 0; j < 4; ++j)
                if (j < tailJ) {
                    const unsigned c0 = v[j].x, c1 = v[j].y, c2 = v[j].z, c3 = v[j].w;
                    acc[j][0] += __uint_as_float(c0 << 16);
                    acc[j][1] += __uint_as_float(c0 & 0xffff0000u);
                    acc[j][2] += __uint_as_float(c1 << 16);
                    acc[j][3] += __uint_as_float(c1 & 0xffff0000u);
                    acc[j][4] += __uint_as_float(c2 << 16);
                    acc[j][5] += __uint_as_float(c2 & 0xffff0000u);
                    acc[j][6] += __uint_as_float(c3 << 16);
                    acc[j][7] += __uint_as_float(c3 & 0xffff0000u);
                }
        }

        #pragma unroll
        for (int f = 0; f < 8; ++f)
            tmp[g][d][f] = acc[0][f] + acc[1][f] + acc[2][f] + acc[3][f];
        __syncthreads();

        if (t < EMB_DIM) {   // dim t = slot(t>>3)*8 + (t&7)
            float s = 0.f;
            #pragma unroll
            for (int gg = 0; gg < 16; ++gg) s += tmp[gg][t >> 3][t & 7];
            Pg[(long)(b0 + r) * EMB_DIM + t] = s / (float)L;
        }
        __syncthreads();     // tmp reused by next row
    }
}

// ---------------------------------------------------------------------------
// Pass 3: MLP. 8 rows/block -> 512 blocks: W1 L2 traffic = 512 x 131 KB =
// 67 MB (vs 268 MB when fused at RB=2). Thread t owns hidden unit t for all
// 8 rows; P-tile reads are block-uniform -> scalar (s_load_dwordx4) loads;
// W1[k*256+t] is fully coalesced (1 KB/wave-load). Layer 2 reads H from LDS
// padded to 257 floats/row so the per-r broadcast groups land in distinct
// banks (conflict-free).
// ---------------------------------------------------------------------------
__global__ __launch_bounds__(256) void mlp_kernel(
    const float* __restrict__ Pg,           // [B, EMB_DIM]
    const float* __restrict__ W1,           // [EMB_DIM, HIDDEN]
    const float* __restrict__ b1,           // [HIDDEN]
    const float* __restrict__ W2,           // [HIDDEN, NUM_CLASSES]
    const float* __restrict__ b2,           // [NUM_CLASSES]
    float* __restrict__ out)                // [B, NUM_CLASSES]
{
    __shared__ float H[MR][HIDDEN + 1];     // +1 pad: layer-2 bank spread

    const int  t  = threadIdx.x;
    const long r0 = (long)blockIdx.x * MR;

    float acc[MR];
    #pragma unroll
    for (int i = 0; i < MR; ++i) acc[i] = 0.f;

    const float* Pb = Pg + r0 * EMB_DIM;
    for (int k = 0; k < EMB_DIM; k += 4) {
        const float w0 = W1[(k + 0) * HIDDEN + t];
        const float w1 = W1[(k + 1) * HIDDEN + t];
        const float w2 = W1[(k + 2) * HIDDEN + t];
        const float w3 = W1[(k + 3) * HIDDEN + t];
        #pragma unroll
        for (int i = 0; i < MR; ++i) {
            const float4 p = *(const float4*)(Pb + i * EMB_DIM + k); // uniform -> s_load
            acc[i] = fmaf(p.x, w0, acc[i]);
            acc[i] = fmaf(p.y, w1, acc[i]);
            acc[i] = fmaf(p.z, w2, acc[i]);
            acc[i] = fmaf(p.w, w3, acc[i]);
        }
    }
    const float bb = b1[t];
    #pragma unroll
    for (int i = 0; i < MR; ++i)
        H[i][t] = fmaxf(acc[i] + bb, 0.f);
    __syncthreads();

    if (t < MR * NUM_CLASSES) {             // 160 threads, 4 indep FMA chains
        const int r = t / NUM_CLASSES;
        const int c = t - r * NUM_CLASSES;
        float a0 = 0.f, a1 = 0.f, a2 = 0.f, a3 = 0.f;
        for (int k = 0; k < HIDDEN; k += 4) {
            a0 = fmaf(H[r][k + 0], W2[(k + 0) * NUM_CLASSES + c], a0);
            a1 = fmaf(H[r][k + 1], W2[(k + 1) * NUM_CLASSES + c], a1);
            a2 = fmaf(H[r][k + 2], W2[(k + 2) * NUM_CLASSES + c], a2);
            a3 = fmaf(H[r][k + 3], W2[(k + 3) * NUM_CLASSES + c], a3);
        }
        out[(r0 + r) * NUM_CLASSES + c] = b2[c] + a0 + a1 + a2 + a3;
    }
}

extern "C" void kernel_launch(void* const* d_in, const int* in_sizes, int n_in,
                              void* d_out, int out_size, void* d_ws, size_t ws_size,
                              hipStream_t stream) {
    const int*   x    = (const int*)d_in[0];
    const int*   lens = (const int*)d_in[1];
    const float* emb  = (const float*)d_in[2];
    const float* W1   = (const float*)d_in[3];
    const float* b1   = (const float*)d_in[4];
    const float* W2   = (const float*)d_in[5];
    const float* b2   = (const float*)d_in[6];
    float*       out  = (float*)d_out;

    unsigned short* embh = (unsigned short*)d_ws;                  // 25.6 MB bf16 table
    float*          Pg   = (float*)((char*)d_ws + (32l << 20));    // 2 MB pooled [B,128]

    // VOCAB*EMB_DIM = 12.8M elems / 8 per thread / 256 per block = 6250 blocks
    convert_kernel<<<(VOCAB * EMB_DIM) / (8 * 256), 256, 0, stream>>>(emb, embh);
    gather_kernel<<<B / RB, 256, 0, stream>>>(x, lens, embh, Pg);
    mlp_kernel<<<B / MR, 256, 0, stream>>>(Pg, W1, b1, W2, b2, out);
}

// Round 2
// 125.197 us; speedup vs baseline: 1.0805x; 1.0805x over previous
//
#include <hip/hip_runtime.h>

#define B 4096
#define S 200
#define EMB_DIM 128
#define HIDDEN 256
#define NUM_CLASSES 20
#define VOCAB 100000
#define RB 2               // batch rows per block

typedef __attribute__((ext_vector_type(8))) unsigned short ushort8;

// RNE float -> bf16 (inputs are finite, no NaN handling needed)
__device__ __forceinline__ unsigned short f2bf(float f) {
    unsigned u = __float_as_uint(f);
    unsigned r = u + 0x7fffu + ((u >> 16) & 1u);
    return (unsigned short)(r >> 16);
}

// ---------------------------------------------------------------------------
// Pass 1: stream-convert the fp32 table (51.2 MB, cold in HBM because the
// harness's 256 MiB ws re-poison flushes L3 every iteration) into a 25.6 MB
// bf16 table in d_ws. Sequential HBM reads at ~6 TB/s; the bf16 table it
// leaves behind is L3-resident for pass 2 and halves the gathered bytes.
// At its 76.8 MB roofline (~12 us) -- not a lever.
// ---------------------------------------------------------------------------
__global__ __launch_bounds__(256) void convert_kernel(
    const float* __restrict__ emb,          // [VOCAB*EMB_DIM]
    unsigned short* __restrict__ embh)      // [VOCAB*EMB_DIM] bf16 bits
{
    const long i = ((long)blockIdx.x * 256 + threadIdx.x) * 8;
    const float4 a = *(const float4*)(emb + i);
    const float4 b = *(const float4*)(emb + i + 4);
    ushort8 o;
    o[0] = f2bf(a.x); o[1] = f2bf(a.y); o[2] = f2bf(a.z); o[3] = f2bf(a.w);
    o[4] = f2bf(b.x); o[5] = f2bf(b.y); o[6] = f2bf(b.z); o[7] = f2bf(b.w);
    *(ushort8*)(embh + i) = o;
}

// ---------------------------------------------------------------------------
// Pass 2: fused gather + mean-pool + MLP, RB=2 rows per block (2048 blocks,
// 256 threads). g = t>>4 (16 position groups), d = t&15 (16B slot of the
// 256B bf16 row).
//
// R1 post-mortem: gather is ROUND-LATENCY-bound (16-granular tail cut 18% of
// work, kept round count, got slower). So this version gathers BOTH rows in
// the same round: 8 loads in flight per vmcnt wait, serial rounds drop from
// E[n0+n1]=4.14 to E[max(n0,n1)]=2.65 (-36%). The shorter row's surplus
// rounds read sidx zeros -> row 0 (all-zero padding row, cache-hot) --
// branch-free. Per-j accumulators merged into acc[2][8] to hold the round-0
// VGPR bracket; both rows' tmp reductions share one barrier pair.
// ---------------------------------------------------------------------------
__global__ __launch_bounds__(256) void fused_kernel(
    const int* __restrict__ x,              // [B, S]
    const int* __restrict__ lens,           // [B]
    const unsigned short* __restrict__ embh,// [VOCAB, EMB_DIM] bf16
    const float* __restrict__ W1,           // [EMB_DIM, HIDDEN]
    const float* __restrict__ b1,           // [HIDDEN]
    const float* __restrict__ W2,           // [HIDDEN, NUM_CLASSES]
    const float* __restrict__ b2,           // [NUM_CLASSES]
    float* __restrict__ out)                // [B, NUM_CLASSES]
{
    __shared__ int   sidx[RB][256];              // 2 KB
    __shared__ float tmp[RB][16][16][8];         // 16 KB (row, group, slot, f)
    __shared__ float P[RB][EMB_DIM];             // 1 KB
    __shared__ float H[RB][HIDDEN];              // 2 KB
    __shared__ float part[RB][4][NUM_CLASSES];   // 640 B

    const int t  = threadIdx.x;
    const int b0 = blockIdx.x * RB;

    int Ls[RB];
    #pragma unroll
    for (int r = 0; r < RB; ++r) {
        Ls[r] = lens[b0 + r];
        int v = 0;
        if (t < Ls[r]) v = x[(long)(b0 + r) * S + t];   // L <= S = 200 < 256
        sidx[r][t] = v;
    }
    __syncthreads();

    const int g = t >> 4;   // position group 0..15
    const int d = t & 15;   // 16B slot within the 256B bf16 row

    const int n0   = (Ls[0] + 63) >> 6;        // 1..4
    const int n1   = (Ls[1] + 63) >> 6;        // 1..4
    const int nMax = n0 > n1 ? n0 : n1;        // block-uniform

    float acc[RB][8];
    #pragma unroll
    for (int r = 0; r < RB; ++r)
        #pragma unroll
        for (int f = 0; f < 8; ++f) acc[r][f] = 0.f;

    int cur[RB][4], nxt[RB][4];
    #pragma unroll
    for (int r = 0; r < RB; ++r)
        #pragma unroll
        for (int j = 0; j < 4; ++j) cur[r][j] = sidx[r][g + 16 * j];

    const int dof = d << 3;                    // element offset of the slot

    for (int it = 0; it < nMax; ++it) {
        uint4 v[RB][4];
        #pragma unroll
        for (int r = 0; r < RB; ++r)
            #pragma unroll
            for (int j = 0; j < 4; ++j)
                v[r][j] = *(const uint4*)(embh + ((cur[r][j] << 7) + dof));

        // prefetch next round's indices before the vmcnt wait
        // (wrap keeps the LDS read in-bounds; values unused on last round)
        const int nb = ((it + 1) & 3) << 6;
        #pragma unroll
        for (int r = 0; r < RB; ++r)
            #pragma unroll
            for (int j = 0; j < 4; ++j) nxt[r][j] = sidx[r][nb + g + 16 * j];

        #pragma unroll
        for (int r = 0; r < RB; ++r)
            #pragma unroll
            for (int j = 0; j < 4; ++j) {
                const unsigned c0 = v[r][j].x, c1 = v[r][j].y;
                const unsigned c2 = v[r][j].z, c3 = v[r][j].w;
                acc[r][0] += __uint_as_float(c0 << 16);
                acc[r][1] += __uint_as_float(c0 & 0xffff0000u);
                acc[r][2] += __uint_as_float(c1 << 16);
                acc[r][3] += __uint_as_float(c1 & 0xffff0000u);
                acc[r][4] += __uint_as_float(c2 << 16);
                acc[r][5] += __uint_as_float(c2 & 0xffff0000u);
                acc[r][6] += __uint_as_float(c3 << 16);
                acc[r][7] += __uint_as_float(c3 & 0xffff0000u);
            }

        #pragma unroll
        for (int r = 0; r < RB; ++r)
            #pragma unroll
            for (int j = 0; j < 4; ++j) cur[r][j] = nxt[r][j];
    }

    #pragma unroll
    for (int r = 0; r < RB; ++r)
        #pragma unroll
        for (int f = 0; f < 8; ++f)
            tmp[r][g][d][f] = acc[r][f];
    __syncthreads();

    // Reduce: 256 threads = 2 rows x 128 dims; stride-1 LDS reads (2-way, free)
    {
        const int r   = t >> 7;
        const int dim = t & 127;
        float s = 0.f;
        #pragma unroll
        for (int gg = 0; gg < 16; ++gg) s += tmp[r][gg][dim >> 3][dim & 7];
        P[r][dim] = s / (float)Ls[r];
    }
    __syncthreads();

    // Layer 1: hidden unit t for both rows; W1 element read once per block.
    {
        float h0a = 0.f, h0b = 0.f, h1a = 0.f, h1b = 0.f;
        for (int k = 0; k < EMB_DIM; k += 2) {
            const float wa = W1[(k)     * HIDDEN + t];
            const float wb = W1[(k + 1) * HIDDEN + t];
            h0a += P[0][k] * wa;  h0b += P[0][k + 1] * wb;
            h1a += P[1][k] * wa;  h1b += P[1][k + 1] * wb;
        }
        const float bb = b1[t];
        H[0][t] = fmaxf(h0a + h0b + bb, 0.f);
        H[1][t] = fmaxf(h1a + h1b + bb, 0.f);
    }
    __syncthreads();

    // Layer 2: RB * 4 k-segments * 20 classes = 160 threads, 64-FMA chains.
    if (t < RB * 4 * NUM_CLASSES) {
        const int r  = t / (4 * NUM_CLASSES);
        const int u  = t - r * 4 * NUM_CLASSES;
        const int j  = u / NUM_CLASSES;
        const int c  = u - j * NUM_CLASSES;
        const int k0 = j * 64;
        float a = 0.f;
        for (int k = k0; k < k0 + 64; ++k)
            a += H[r][k] * W2[k * NUM_CLASSES + c];
        part[r][j][c] = a;
    }
    __syncthreads();

    if (t < RB * NUM_CLASSES) {
        const int r = t / NUM_CLASSES;
        const int c = t - r * NUM_CLASSES;
        const float a = b2[c] + part[r][0][c] + part[r][1][c]
                              + part[r][2][c] + part[r][3][c];
        out[(long)(b0 + r) * NUM_CLASSES + c] = a;
    }
}

extern "C" void kernel_launch(void* const* d_in, const int* in_sizes, int n_in,
                              void* d_out, int out_size, void* d_ws, size_t ws_size,
                              hipStream_t stream) {
    const int*   x    = (const int*)d_in[0];
    const int*   lens = (const int*)d_in[1];
    const float* emb  = (const float*)d_in[2];
    const float* W1   = (const float*)d_in[3];
    const float* b1   = (const float*)d_in[4];
    const float* W2   = (const float*)d_in[5];
    const float* b2   = (const float*)d_in[6];
    float*       out  = (float*)d_out;

    unsigned short* embh = (unsigned short*)d_ws;   // 25.6 MB bf16 table

    // VOCAB*EMB_DIM = 12.8M elems / 8 per thread / 256 per block = 6250 blocks
    convert_kernel<<<(VOCAB * EMB_DIM) / (8 * 256), 256, 0, stream>>>(emb, embh);
    fused_kernel<<<B / RB, 256, 0, stream>>>(x, lens, embh, W1, b1, W2, b2, out);
}